// Round 3
// baseline (539.935 us; speedup 1.0000x reference)
//
#include <hip/hip_runtime.h>
#include <hip/hip_bf16.h>

// out[k,s] = sum_{g: seq[g]==k} exp(A[gi,s] + 1 - pos[g]*B[gi,s]),
// N=1000, S=32, M=2M, K=100k.
//
// Round 3: all random global traffic removed. HW model from rounds 1-2:
// random line-granularity atomics/stores cost ~15G lines/s; coalesced BW is
// 6.3 TB/s. So: bucket genes by seq>>7 (782 buckets of 128 seqs) with a
// block-local counting sort (hist matrix + column scan -> zero global
// atomics, wave-coalesced payload writes), then one block per bucket
// accumulates into a 16KB LDS tile with ds_add_f32 and writes out coalesced.

#define CHUNK 8192        // genes per partition block
#define NBMAX 1024        // max buckets (K <= 131072)
#define PMAX  3072        // payload staging per reduce iteration

// ---- 1: per-block histogram -> hist matrix (u16, coalesced) ---------------
__global__ __launch_bounds__(256) void hist_kernel(
    const int* __restrict__ sidx, unsigned short* __restrict__ histmat,
    int M, int NB)
{
    __shared__ int h[NBMAX];
    const int t = threadIdx.x, blk = blockIdx.x;
    const int i0 = blk * CHUNK;
    const int n = min(CHUNK, M - i0);
    for (int j = t; j < NBMAX; j += 256) h[j] = 0;
    __syncthreads();
    for (int j = t; j < n; j += 256) atomicAdd(&h[sidx[i0 + j] >> 7], 1);
    __syncthreads();
    for (int j = t; j < NB; j += 256)
        histmat[(size_t)blk * NB + j] = (unsigned short)h[j];
}

// ---- 2: column-wise exclusive scan over blocks -> cursors + bucket counts -
__global__ __launch_bounds__(256) void colscan_kernel(
    const unsigned short* __restrict__ histmat, unsigned short* __restrict__ cursors,
    int* __restrict__ cnt, int NB, int NBLK)
{
    const int b = blockIdx.x * 256 + threadIdx.x;
    if (b >= NB) return;
    int run = 0;
    for (int blk = 0; blk < NBLK; blk++) {
        const size_t id = (size_t)blk * NB + b;
        const int v = histmat[id];
        cursors[id] = (unsigned short)run;
        run += v;
    }
    cnt[b] = run;
}

// ---- 3: exclusive scan of bucket counts -> base[NB+1] ---------------------
__global__ __launch_bounds__(256) void basescan_kernel(
    const int* __restrict__ cnt, int* __restrict__ base, int NB)
{
    __shared__ int ssum[256];
    const int t = threadIdx.x;
    int v[4], s = 0;
#pragma unroll
    for (int j = 0; j < 4; j++) {
        const int idx = t * 4 + j;
        v[j] = (idx < NB) ? cnt[idx] : 0;
        s += v[j];
    }
    ssum[t] = s;
    __syncthreads();
    for (int d = 1; d < 256; d <<= 1) {
        const int x = (t >= d) ? ssum[t - d] : 0;
        __syncthreads();
        ssum[t] += x;
        __syncthreads();
    }
    int run = (t > 0) ? ssum[t - 1] : 0;
#pragma unroll
    for (int j = 0; j < 4; j++) {
        const int idx = t * 4 + j;
        if (idx <= NB) base[idx] = run;   // exclusive prefix; base[NB] = total
        run += v[j];
    }
}

// ---- 4: block-local counting sort -> coalesced payload write --------------
__global__ __launch_bounds__(256) void partition_kernel(
    const float* __restrict__ pos, const int* __restrict__ gidx,
    const int* __restrict__ sidx,
    const unsigned short* __restrict__ cursors, const int* __restrict__ base,
    int2* __restrict__ payload, int M, int NB)
{
    __shared__ int h[NBMAX];      // hist
    __shared__ int pfx[NBMAX];    // exclusive prefix (kept)
    __shared__ int cur[NBMAX];    // running cursor for placement
    __shared__ int ssum[256];
    __shared__ int2 stg[CHUNK];   // 64 KB staging
    const int t = threadIdx.x, blk = blockIdx.x;
    const int i0 = blk * CHUNK;
    const int n = min(CHUNK, M - i0);

    for (int j = t; j < NBMAX; j += 256) h[j] = 0;
    __syncthreads();
    for (int j = t; j < n; j += 256) atomicAdd(&h[sidx[i0 + j] >> 7], 1);
    __syncthreads();

    // block scan of h -> pfx, cur
    int v[4], s = 0;
#pragma unroll
    for (int j = 0; j < 4; j++) { v[j] = h[t * 4 + j]; s += v[j]; }
    ssum[t] = s;
    __syncthreads();
    for (int d = 1; d < 256; d <<= 1) {
        const int x = (t >= d) ? ssum[t - d] : 0;
        __syncthreads();
        ssum[t] += x;
        __syncthreads();
    }
    int run = (t > 0) ? ssum[t - 1] : 0;
#pragma unroll
    for (int j = 0; j < 4; j++) {
        pfx[t * 4 + j] = run;
        cur[t * 4 + j] = run;
        run += v[j];
    }
    __syncthreads();

    // placement into LDS staging (sorted by bucket)
    for (int j = t; j < n; j += 256) {
        const int sx = sidx[i0 + j];
        const int b = sx >> 7;
        const int d = atomicAdd(&cur[b], 1);
        int2 pl;
        pl.x = __float_as_int(pos[i0 + j]);
        pl.y = sx | (gidx[i0 + j] << 17);    // sidx: 17 bits, gidx: 10 bits
        stg[d] = pl;
    }
    __syncthreads();

    // coalesced flush: consecutive threads -> consecutive global slots
    for (int tt = t; tt < n; tt += 256) {
        const int2 pl = stg[tt];
        const int sx = pl.y & 0x1FFFF;
        const int b = sx >> 7;
        const int gdest = base[b] + (int)cursors[(size_t)blk * NB + b] + (tt - pfx[b]);
        payload[gdest] = pl;
    }
}

// ---- 5: one block per bucket, LDS accumulate, coalesced out ---------------
__global__ __launch_bounds__(256) void reduce_kernel(
    const float* __restrict__ A, const float* __restrict__ B,
    const int2* __restrict__ payload, const int* __restrict__ base,
    float* __restrict__ out, int K)
{
    __shared__ float o[128 * 32];   // 16 KB: this bucket's 128 seq rows
    __shared__ int2 pay[PMAX];      // 24 KB staging
    const int t = threadIdx.x, bkt = blockIdx.x;
    const int start = base[bkt], end = base[bkt + 1];
    const int lane = t & 31, grp = t >> 5;
    for (int j = t; j < 4096; j += 256) o[j] = 0.0f;

    for (int c = start; c < end; c += PMAX) {
        const int cn = min(PMAX, end - c);
        __syncthreads();
        for (int j = t; j < cn; j += 256) pay[j] = payload[c + j];
        __syncthreads();
#pragma unroll 4
        for (int j = grp; j < cn; j += 8) {
            const int2 pl = pay[j];                 // LDS broadcast (32 lanes)
            const float p = __int_as_float(pl.x);
            const int sx = pl.y & 0x1FFFF;
            const int gi = pl.y >> 17;
            const int sl = sx & 127;
            const float a = A[(gi << 5) + lane];    // 128B coalesced, L2-hit
            const float b = B[(gi << 5) + lane];
            const float vv = __expf(fmaf(-p, b, a + 1.0f));
            atomicAdd(&o[(sl << 5) + lane], vv);    // ds_add_f32, 2 rows/wave
        }
    }
    __syncthreads();
    const int seq0 = bkt << 7;
    for (int j = t; j < 4096; j += 256) {
        const int seq = seq0 + (j >> 5);
        if (seq < K) out[seq * 32 + (j & 31)] = o[j];
    }
}

// ---- fallback (round-1 atomic version) ------------------------------------
__global__ __launch_bounds__(256) void scatter_exp_fallback(
    const float* __restrict__ A, const float* __restrict__ B,
    const float* __restrict__ pos, const int* __restrict__ gidx,
    const int* __restrict__ sidx, float* __restrict__ out, int M)
{
    const int lane = threadIdx.x & 31;
    int group = (int)((blockIdx.x * blockDim.x + threadIdx.x) >> 5);
    const int stride = (int)((gridDim.x * blockDim.x) >> 5);
    for (int g = group; g < M; g += stride) {
        const int gi = gidx[g];
        const int si = sidx[g];
        const float p = pos[g];
        const float a = A[(gi << 5) + lane];
        const float b = B[(gi << 5) + lane];
        atomicAdd(&out[(si << 5) + lane], __expf(fmaf(-p, b, a + 1.0f)));
    }
}

extern "C" void kernel_launch(void* const* d_in, const int* in_sizes, int n_in,
                              void* d_out, int out_size, void* d_ws, size_t ws_size,
                              hipStream_t stream)
{
    const float* A    = (const float*)d_in[0];   // [N,32]
    const float* B    = (const float*)d_in[1];   // [N,32]
    const float* pos  = (const float*)d_in[2];   // [M]
    const int*   gidx = (const int*)d_in[3];     // [M]
    const int*   sidx = (const int*)d_in[4];     // [M]
    float*       out  = (float*)d_out;           // [K,32]

    const int M = in_sizes[2];
    const int K = out_size / 32;
    const int NB = (K + 127) >> 7;               // 782 for K=100k
    const int NBLK = (M + CHUNK - 1) / CHUNK;    // 245 for M=2M

    // ws layout: histmat u16[NBLK*NB] | cursors u16[NBLK*NB] | cnt i32[1024]
    //            | base i32[1025] | payload int2[M]
    char* ws = (char*)d_ws;
    const size_t matbytes = (size_t)NBLK * NB * sizeof(unsigned short);
    unsigned short* histmat = (unsigned short*)ws;
    unsigned short* cursors = (unsigned short*)(ws + matbytes);
    size_t off = 2 * matbytes;
    off = (off + 3) & ~(size_t)3;
    int* cnt  = (int*)(ws + off);  off += (size_t)NBMAX * sizeof(int);
    int* base = (int*)(ws + off);  off += (size_t)(NBMAX + 1) * sizeof(int);
    off = (off + 15) & ~(size_t)15;
    int2* payload = (int2*)(ws + off);
    const size_t need = off + (size_t)M * sizeof(int2);

    // gidx must fit 10 bits << 17, sidx 17 bits, NB <= NBMAX
    const bool packable = (NB <= NBMAX);
    if (!packable || ws_size < need) {
        hipMemsetAsync(d_out, 0, (size_t)out_size * sizeof(float), stream);
        scatter_exp_fallback<<<8192, 256, 0, stream>>>(A, B, pos, gidx, sidx, out, M);
        return;
    }

    hist_kernel    <<<NBLK, 256, 0, stream>>>(sidx, histmat, M, NB);
    colscan_kernel <<<(NB + 255) / 256, 256, 0, stream>>>(histmat, cursors, cnt, NB, NBLK);
    basescan_kernel<<<1, 256, 0, stream>>>(cnt, base, NB);
    partition_kernel<<<NBLK, 256, 0, stream>>>(pos, gidx, sidx, cursors, base, payload, M, NB);
    reduce_kernel  <<<NB, 256, 0, stream>>>(A, B, payload, base, out, K);
}

// Round 4
// 485.663 us; speedup vs baseline: 1.1117x; 1.1117x over previous
//
#include <hip/hip_runtime.h>
#include <hip/hip_bf16.h>

// out[k,s] = sum_{g: seq[g]==k} exp(A[gi,s] + 1 - pos[g]*B[gi,s]),
// N=1000, S=32, M=2M, K=100k.
//
// Round 4: partition machinery (zero global atomics) unchanged from round 3.
// Reduce rebuilt for latency tolerance: no LDS staging/barriers, 16KB LDS,
// 2 blocks per bucket (split payload range), 4-wide independent gene chains,
// coalesced global-atomic flush. Round-3 reduce was latency-serialized
// (435us, VALUBusy 5.7%, occupancy 27%).

#define CHUNK 8192        // genes per partition block
#define NBMAX 1024        // max buckets (K <= 131072)
#define SPLIT 2           // reduce blocks per bucket

// ---- 1: per-block histogram -> hist matrix (u16, coalesced) ---------------
__global__ __launch_bounds__(256) void hist_kernel(
    const int* __restrict__ sidx, unsigned short* __restrict__ histmat,
    int M, int NB)
{
    __shared__ int h[NBMAX];
    const int t = threadIdx.x, blk = blockIdx.x;
    const int i0 = blk * CHUNK;
    const int n = min(CHUNK, M - i0);
    for (int j = t; j < NBMAX; j += 256) h[j] = 0;
    __syncthreads();
    for (int j = t; j < n; j += 256) atomicAdd(&h[sidx[i0 + j] >> 7], 1);
    __syncthreads();
    for (int j = t; j < NB; j += 256)
        histmat[(size_t)blk * NB + j] = (unsigned short)h[j];
}

// ---- 2: column-wise exclusive scan over blocks -> cursors + bucket counts -
__global__ __launch_bounds__(256) void colscan_kernel(
    const unsigned short* __restrict__ histmat, unsigned short* __restrict__ cursors,
    int* __restrict__ cnt, int NB, int NBLK)
{
    const int b = blockIdx.x * 256 + threadIdx.x;
    if (b >= NB) return;
    int run = 0;
    for (int blk = 0; blk < NBLK; blk++) {
        const size_t id = (size_t)blk * NB + b;
        const int v = histmat[id];
        cursors[id] = (unsigned short)run;
        run += v;
    }
    cnt[b] = run;
}

// ---- 3: exclusive scan of bucket counts -> base[NB+1] ---------------------
__global__ __launch_bounds__(256) void basescan_kernel(
    const int* __restrict__ cnt, int* __restrict__ base, int NB)
{
    __shared__ int ssum[256];
    const int t = threadIdx.x;
    int v[4], s = 0;
#pragma unroll
    for (int j = 0; j < 4; j++) {
        const int idx = t * 4 + j;
        v[j] = (idx < NB) ? cnt[idx] : 0;
        s += v[j];
    }
    ssum[t] = s;
    __syncthreads();
    for (int d = 1; d < 256; d <<= 1) {
        const int x = (t >= d) ? ssum[t - d] : 0;
        __syncthreads();
        ssum[t] += x;
        __syncthreads();
    }
    int run = (t > 0) ? ssum[t - 1] : 0;
#pragma unroll
    for (int j = 0; j < 4; j++) {
        const int idx = t * 4 + j;
        if (idx <= NB) base[idx] = run;   // exclusive prefix; base[NB] = total
        run += v[j];
    }
}

// ---- 4: block-local counting sort -> coalesced payload write --------------
__global__ __launch_bounds__(256) void partition_kernel(
    const float* __restrict__ pos, const int* __restrict__ gidx,
    const int* __restrict__ sidx,
    const unsigned short* __restrict__ cursors, const int* __restrict__ base,
    int2* __restrict__ payload, int M, int NB)
{
    __shared__ int h[NBMAX];      // hist
    __shared__ int pfx[NBMAX];    // exclusive prefix (kept)
    __shared__ int cur[NBMAX];    // running cursor for placement
    __shared__ int ssum[256];
    __shared__ int2 stg[CHUNK];   // 64 KB staging
    const int t = threadIdx.x, blk = blockIdx.x;
    const int i0 = blk * CHUNK;
    const int n = min(CHUNK, M - i0);

    for (int j = t; j < NBMAX; j += 256) h[j] = 0;
    __syncthreads();
    for (int j = t; j < n; j += 256) atomicAdd(&h[sidx[i0 + j] >> 7], 1);
    __syncthreads();

    // block scan of h -> pfx, cur
    int v[4], s = 0;
#pragma unroll
    for (int j = 0; j < 4; j++) { v[j] = h[t * 4 + j]; s += v[j]; }
    ssum[t] = s;
    __syncthreads();
    for (int d = 1; d < 256; d <<= 1) {
        const int x = (t >= d) ? ssum[t - d] : 0;
        __syncthreads();
        ssum[t] += x;
        __syncthreads();
    }
    int run = (t > 0) ? ssum[t - 1] : 0;
#pragma unroll
    for (int j = 0; j < 4; j++) {
        pfx[t * 4 + j] = run;
        cur[t * 4 + j] = run;
        run += v[j];
    }
    __syncthreads();

    // placement into LDS staging (sorted by bucket)
    for (int j = t; j < n; j += 256) {
        const int sx = sidx[i0 + j];
        const int b = sx >> 7;
        const int d = atomicAdd(&cur[b], 1);
        int2 pl;
        pl.x = __float_as_int(pos[i0 + j]);
        pl.y = sx | (gidx[i0 + j] << 17);    // sidx: 17 bits, gidx: 10 bits
        stg[d] = pl;
    }
    __syncthreads();

    // coalesced flush: consecutive threads -> consecutive global slots
    for (int tt = t; tt < n; tt += 256) {
        const int2 pl = stg[tt];
        const int sx = pl.y & 0x1FFFF;
        const int b = sx >> 7;
        const int gdest = base[b] + (int)cursors[(size_t)blk * NB + b] + (tt - pfx[b]);
        payload[gdest] = pl;
    }
}

// ---- 5: reduce — SPLIT blocks per bucket, 16KB LDS tile, 4-wide chains ----
#define PROC(pl)                                                         \
    {                                                                    \
        const float p  = __int_as_float((pl).x);                         \
        const int   sx = (pl).y & 0x1FFFF;                               \
        const int   gi = (pl).y >> 17;                                   \
        const float a  = A[(gi << 5) + lane];                            \
        const float b  = B[(gi << 5) + lane];                            \
        const float vv = __expf(fmaf(-p, b, a + 1.0f));                  \
        atomicAdd(&o[((sx & 127) << 5) + lane], vv);                     \
    }

__global__ __launch_bounds__(256) void reduce_kernel(
    const float* __restrict__ A, const float* __restrict__ B,
    const int2* __restrict__ payload, const int* __restrict__ base,
    float* __restrict__ out, int K)
{
    __shared__ float o[128 * 32];   // 16 KB
    const int t = threadIdx.x;
    const int bkt = blockIdx.x >> 1;         // SPLIT=2
    const int sp  = blockIdx.x & 1;
    const int start = base[bkt], end = base[bkt + 1];
    const int len = end - start;
    const int c0 = start + ((len * sp) >> 1);
    const int c1 = start + ((len * (sp + 1)) >> 1);
    const int lane = t & 31, grp = t >> 5;

    for (int j = t; j < 4096; j += 256) o[j] = 0.0f;
    __syncthreads();

    // each 32-lane group: entries c0+grp, +8, +16, ... ; 4 independent chains
    int j = c0 + grp;
    for (; j + 24 < c1; j += 32) {
        const int2 p0 = payload[j];
        const int2 p1 = payload[j + 8];
        const int2 p2 = payload[j + 16];
        const int2 p3 = payload[j + 24];
        PROC(p0); PROC(p1); PROC(p2); PROC(p3);
    }
    for (; j < c1; j += 8) {
        const int2 p0 = payload[j];
        PROC(p0);
    }
    __syncthreads();

    // coalesced atomic flush (out pre-zeroed; two split-blocks add)
    const int seq0 = bkt << 7;
    for (int j2 = t; j2 < 4096; j2 += 256) {
        const int seq = seq0 + (j2 >> 5);
        if (seq < K) atomicAdd(&out[seq * 32 + (j2 & 31)], o[j2]);
    }
}

// ---- fallback (round-1 atomic version) ------------------------------------
__global__ __launch_bounds__(256) void scatter_exp_fallback(
    const float* __restrict__ A, const float* __restrict__ B,
    const float* __restrict__ pos, const int* __restrict__ gidx,
    const int* __restrict__ sidx, float* __restrict__ out, int M)
{
    const int lane = threadIdx.x & 31;
    int group = (int)((blockIdx.x * blockDim.x + threadIdx.x) >> 5);
    const int stride = (int)((gridDim.x * blockDim.x) >> 5);
    for (int g = group; g < M; g += stride) {
        const int gi = gidx[g];
        const int si = sidx[g];
        const float p = pos[g];
        const float a = A[(gi << 5) + lane];
        const float b = B[(gi << 5) + lane];
        atomicAdd(&out[(si << 5) + lane], __expf(fmaf(-p, b, a + 1.0f)));
    }
}

extern "C" void kernel_launch(void* const* d_in, const int* in_sizes, int n_in,
                              void* d_out, int out_size, void* d_ws, size_t ws_size,
                              hipStream_t stream)
{
    const float* A    = (const float*)d_in[0];   // [N,32]
    const float* B    = (const float*)d_in[1];   // [N,32]
    const float* pos  = (const float*)d_in[2];   // [M]
    const int*   gidx = (const int*)d_in[3];     // [M]
    const int*   sidx = (const int*)d_in[4];     // [M]
    float*       out  = (float*)d_out;           // [K,32]

    const int M = in_sizes[2];
    const int K = out_size / 32;
    const int NB = (K + 127) >> 7;               // 782 for K=100k
    const int NBLK = (M + CHUNK - 1) / CHUNK;    // 245 for M=2M

    // ws layout: histmat u16[NBLK*NB] | cursors u16[NBLK*NB] | cnt i32[1024]
    //            | base i32[1025] | payload int2[M]
    char* ws = (char*)d_ws;
    const size_t matbytes = (size_t)NBLK * NB * sizeof(unsigned short);
    unsigned short* histmat = (unsigned short*)ws;
    unsigned short* cursors = (unsigned short*)(ws + matbytes);
    size_t off = 2 * matbytes;
    off = (off + 3) & ~(size_t)3;
    int* cnt  = (int*)(ws + off);  off += (size_t)NBMAX * sizeof(int);
    int* base = (int*)(ws + off);  off += (size_t)(NBMAX + 1) * sizeof(int);
    off = (off + 15) & ~(size_t)15;
    int2* payload = (int2*)(ws + off);
    const size_t need = off + (size_t)M * sizeof(int2);

    const bool packable = (NB <= NBMAX);
    if (!packable || ws_size < need) {
        hipMemsetAsync(d_out, 0, (size_t)out_size * sizeof(float), stream);
        scatter_exp_fallback<<<8192, 256, 0, stream>>>(A, B, pos, gidx, sidx, out, M);
        return;
    }

    hipMemsetAsync(d_out, 0, (size_t)out_size * sizeof(float), stream);
    hist_kernel    <<<NBLK, 256, 0, stream>>>(sidx, histmat, M, NB);
    colscan_kernel <<<(NB + 255) / 256, 256, 0, stream>>>(histmat, cursors, cnt, NB, NBLK);
    basescan_kernel<<<1, 256, 0, stream>>>(cnt, base, NB);
    partition_kernel<<<NBLK, 256, 0, stream>>>(pos, gidx, sidx, cursors, base, payload, M, NB);
    reduce_kernel  <<<NB * SPLIT, 256, 0, stream>>>(A, B, payload, base, out, K);
}

// Round 5
// 156.345 us; speedup vs baseline: 3.4535x; 3.1064x over previous
//
#include <hip/hip_runtime.h>
#include <hip/hip_bf16.h>

// out[k,s] = sum_{g: seq[g]==k} exp(A[gi,s] + 1 - pos[g]*B[gi,s]),
// N=1000, S=32, M=2M, K=100k.
//
// Round 5 model (from rounds 1-4 evidence):
//  - random global line-txns ~15 G/s (rounds 1,2)
//  - per-lane LDS f32 atomics ~0.7 RMW/cy/CU -> 64M of them = ~375us floor
//    (rounds 3,4: two different reduce structures, same time, all pipes idle)
// Therefore: ZERO per-lane atomics. Bucket-partition (per-gene ops only),
// then fused per-bucket counting-sort-by-seq + register accumulation, with
// exclusive seq ownership per 32-lane group and coalesced stores.

#define CHUNK 8192        // genes per partition block
#define NBMAX 1024        // max buckets (K <= 131072)
#define SORTC 3072        // sorted-chunk capacity in fused reduce

// ---- 1: per-block histogram -> hist matrix (u16, coalesced) ---------------
__global__ __launch_bounds__(256) void hist_kernel(
    const int* __restrict__ sidx, unsigned short* __restrict__ histmat,
    int M, int NB)
{
    __shared__ int h[NBMAX];
    const int t = threadIdx.x, blk = blockIdx.x;
    const int i0 = blk * CHUNK;
    const int n = min(CHUNK, M - i0);
    for (int j = t; j < NBMAX; j += 256) h[j] = 0;
    __syncthreads();
    for (int j = t; j < n; j += 256) atomicAdd(&h[sidx[i0 + j] >> 7], 1);
    __syncthreads();
    for (int j = t; j < NB; j += 256)
        histmat[(size_t)blk * NB + j] = (unsigned short)h[j];
}

// ---- 2: column-wise exclusive scan over blocks -> cursors + bucket counts -
__global__ __launch_bounds__(256) void colscan_kernel(
    const unsigned short* __restrict__ histmat, unsigned short* __restrict__ cursors,
    int* __restrict__ cnt, int NB, int NBLK)
{
    const int b = blockIdx.x * 256 + threadIdx.x;
    if (b >= NB) return;
    int run = 0;
    for (int blk = 0; blk < NBLK; blk++) {
        const size_t id = (size_t)blk * NB + b;
        const int v = histmat[id];
        cursors[id] = (unsigned short)run;
        run += v;
    }
    cnt[b] = run;
}

// ---- 3: exclusive scan of bucket counts -> base[NB+1] ---------------------
__global__ __launch_bounds__(256) void basescan_kernel(
    const int* __restrict__ cnt, int* __restrict__ base, int NB)
{
    __shared__ int ssum[256];
    const int t = threadIdx.x;
    int v[4], s = 0;
#pragma unroll
    for (int j = 0; j < 4; j++) {
        const int idx = t * 4 + j;
        v[j] = (idx < NB) ? cnt[idx] : 0;
        s += v[j];
    }
    ssum[t] = s;
    __syncthreads();
    for (int d = 1; d < 256; d <<= 1) {
        const int x = (t >= d) ? ssum[t - d] : 0;
        __syncthreads();
        ssum[t] += x;
        __syncthreads();
    }
    int run = (t > 0) ? ssum[t - 1] : 0;
#pragma unroll
    for (int j = 0; j < 4; j++) {
        const int idx = t * 4 + j;
        if (idx <= NB) base[idx] = run;   // exclusive prefix; base[NB] = total
        run += v[j];
    }
}

// ---- 4: block-local counting sort -> coalesced payload write --------------
// Flush destinations precomputed into LDS (reusing cur[]) — kills the 4M
// uncoalesced global gathers of base[]/cursors[] that cost ~110us in r3/r4.
__global__ __launch_bounds__(256) void partition_kernel(
    const float* __restrict__ pos, const int* __restrict__ gidx,
    const int* __restrict__ sidx,
    const unsigned short* __restrict__ cursors, const int* __restrict__ base,
    int2* __restrict__ payload, int M, int NB)
{
    __shared__ int h[NBMAX];      // hist
    __shared__ int pfx[NBMAX];    // exclusive prefix (kept)
    __shared__ int cur[NBMAX];    // cursor for placement, then dest-base
    __shared__ int ssum[256];
    __shared__ int2 stg[CHUNK];   // 64 KB staging
    const int t = threadIdx.x, blk = blockIdx.x;
    const int i0 = blk * CHUNK;
    const int n = min(CHUNK, M - i0);

    for (int j = t; j < NBMAX; j += 256) h[j] = 0;
    __syncthreads();
    for (int j = t; j < n; j += 256) atomicAdd(&h[sidx[i0 + j] >> 7], 1);
    __syncthreads();

    // block scan of h -> pfx, cur
    int v[4], s = 0;
#pragma unroll
    for (int j = 0; j < 4; j++) { v[j] = h[t * 4 + j]; s += v[j]; }
    ssum[t] = s;
    __syncthreads();
    for (int d = 1; d < 256; d <<= 1) {
        const int x = (t >= d) ? ssum[t - d] : 0;
        __syncthreads();
        ssum[t] += x;
        __syncthreads();
    }
    int run = (t > 0) ? ssum[t - 1] : 0;
#pragma unroll
    for (int j = 0; j < 4; j++) {
        pfx[t * 4 + j] = run;
        cur[t * 4 + j] = run;
        run += v[j];
    }
    __syncthreads();

    // placement into LDS staging (sorted by bucket)
    for (int j = t; j < n; j += 256) {
        const int sx = sidx[i0 + j];
        const int b = sx >> 7;
        const int d = atomicAdd(&cur[b], 1);
        int2 pl;
        pl.x = __float_as_int(pos[i0 + j]);
        pl.y = sx | (gidx[i0 + j] << 17);    // sidx: 17 bits, gidx: 14 bits
        stg[d] = pl;
    }
    __syncthreads();

    // precompute per-bucket global destination base into cur[] (coalesced reads)
    for (int b = t; b < NB; b += 256)
        cur[b] = base[b] + (int)cursors[(size_t)blk * NB + b];
    __syncthreads();

    // coalesced flush: consecutive threads -> consecutive global slots
    for (int tt = t; tt < n; tt += 256) {
        const int2 pl = stg[tt];
        const int b = (pl.y & 0x1FFFF) >> 7;
        payload[cur[b] + (tt - pfx[b])] = pl;
    }
}

// ---- 5: fused per-bucket sort-by-seq + register-accumulate reduce ---------
// 1024 threads = 32 groups of 32 lanes; each group OWNS local seqs
// [4*grp, 4*grp+4) -> acc in registers, no atomics in the 32-wide phase.
__global__ __launch_bounds__(1024, 8) void fused_reduce_kernel(
    const float* __restrict__ A, const float* __restrict__ B,
    const int2* __restrict__ payload, const int* __restrict__ base,
    float* __restrict__ out, int K)
{
    __shared__ int2 sorted[SORTC];    // 24 KB
    __shared__ int h[128];            // per-chunk counts per local seq
    __shared__ int pfx[128];          // exclusive prefix
    __shared__ int cur[128];          // scatter cursor
    __shared__ int sc[128];           // scan scratch
    const int t = threadIdx.x, bkt = blockIdx.x;
    const int lane = t & 31, grp = t >> 5;
    const int start = base[bkt], end = base[bkt + 1];

    float acc[4] = {0.0f, 0.0f, 0.0f, 0.0f};

    for (int c = start; c < end; c += SORTC) {
        const int n = min(SORTC, end - c);

        if (t < 128) h[t] = 0;
        __syncthreads();

        // load up to 3 entries/thread (coalesced), LDS int histogram
        int2 r0, r1, r2;
        const bool v0 = t < n, v1 = t + 1024 < n, v2 = t + 2048 < n;
        if (v0) { r0 = payload[c + t];        atomicAdd(&h[r0.y & 127], 1); }
        if (v1) { r1 = payload[c + t + 1024]; atomicAdd(&h[r1.y & 127], 1); }
        if (v2) { r2 = payload[c + t + 2048]; atomicAdd(&h[r2.y & 127], 1); }
        __syncthreads();

        // inclusive scan of h over 128 entries (Hillis-Steele, block-wide)
        if (t < 128) sc[t] = h[t];
        __syncthreads();
        for (int d = 1; d < 128; d <<= 1) {
            int x = 0;
            if (t < 128 && t >= d) x = sc[t - d];
            __syncthreads();
            if (t < 128) sc[t] += x;
            __syncthreads();
        }
        if (t < 128) { pfx[t] = sc[t] - h[t]; cur[t] = sc[t] - h[t]; }
        __syncthreads();

        // scatter into sorted[] by local seq
        if (v0) sorted[atomicAdd(&cur[r0.y & 127], 1)] = r0;
        if (v1) sorted[atomicAdd(&cur[r1.y & 127], 1)] = r1;
        if (v2) sorted[atomicAdd(&cur[r2.y & 127], 1)] = r2;
        __syncthreads();

        // register-accumulate: group grp owns local seqs 4*grp .. 4*grp+3
#pragma unroll
        for (int q = 0; q < 4; q++) {
            const int ls = (grp << 2) | q;
            const int s0 = pfx[ls];
            const int cnt = h[ls];
            for (int i = 0; i < cnt; i++) {
                const int2 pl = sorted[s0 + i];       // ds_read_b64 broadcast
                const float p = __int_as_float(pl.x);
                const int gi = pl.y >> 17;
                const float a = A[(gi << 5) + lane];  // 128B coalesced, L2-hit
                const float b = B[(gi << 5) + lane];
                acc[q] += __expf(fmaf(-p, b, a + 1.0f));
            }
        }
        __syncthreads();   // before next chunk overwrites h/pfx/sorted
    }

    // coalesced stores; every out element covered exactly once -> no memset
    const int seq0 = bkt << 7;
#pragma unroll
    for (int q = 0; q < 4; q++) {
        const int seq = seq0 + (grp << 2) + q;
        if (seq < K) out[(seq << 5) + lane] = acc[q];
    }
}

// ---- fallback (round-1 atomic version) ------------------------------------
__global__ __launch_bounds__(256) void scatter_exp_fallback(
    const float* __restrict__ A, const float* __restrict__ B,
    const float* __restrict__ pos, const int* __restrict__ gidx,
    const int* __restrict__ sidx, float* __restrict__ out, int M)
{
    const int lane = threadIdx.x & 31;
    int group = (int)((blockIdx.x * blockDim.x + threadIdx.x) >> 5);
    const int stride = (int)((gridDim.x * blockDim.x) >> 5);
    for (int g = group; g < M; g += stride) {
        const int gi = gidx[g];
        const int si = sidx[g];
        const float p = pos[g];
        const float a = A[(gi << 5) + lane];
        const float b = B[(gi << 5) + lane];
        atomicAdd(&out[(si << 5) + lane], __expf(fmaf(-p, b, a + 1.0f)));
    }
}

extern "C" void kernel_launch(void* const* d_in, const int* in_sizes, int n_in,
                              void* d_out, int out_size, void* d_ws, size_t ws_size,
                              hipStream_t stream)
{
    const float* A    = (const float*)d_in[0];   // [N,32]
    const float* B    = (const float*)d_in[1];   // [N,32]
    const float* pos  = (const float*)d_in[2];   // [M]
    const int*   gidx = (const int*)d_in[3];     // [M]
    const int*   sidx = (const int*)d_in[4];     // [M]
    float*       out  = (float*)d_out;           // [K,32]

    const int M = in_sizes[2];
    const int N = in_sizes[0] / 32;
    const int K = out_size / 32;
    const int NB = (K + 127) >> 7;               // 782 for K=100k
    const int NBLK = (M + CHUNK - 1) / CHUNK;    // 245 for M=2M

    // ws layout: histmat u16[NBLK*NB] | cursors u16[NBLK*NB] | cnt i32[1024]
    //            | base i32[1025] | payload int2[M]
    char* ws = (char*)d_ws;
    const size_t matbytes = (size_t)NBLK * NB * sizeof(unsigned short);
    unsigned short* histmat = (unsigned short*)ws;
    unsigned short* cursors = (unsigned short*)(ws + matbytes);
    size_t off = 2 * matbytes;
    off = (off + 3) & ~(size_t)3;
    int* cnt  = (int*)(ws + off);  off += (size_t)NBMAX * sizeof(int);
    int* base = (int*)(ws + off);  off += (size_t)(NBMAX + 1) * sizeof(int);
    off = (off + 15) & ~(size_t)15;
    int2* payload = (int2*)(ws + off);
    const size_t need = off + (size_t)M * sizeof(int2);

    // pack limits: sidx 17 bits (K<=131072), gidx 14 bits (N<=16384)
    const bool packable = (NB <= NBMAX) && (K <= 131072) && (N <= 16384);
    if (!packable || ws_size < need) {
        hipMemsetAsync(d_out, 0, (size_t)out_size * sizeof(float), stream);
        scatter_exp_fallback<<<8192, 256, 0, stream>>>(A, B, pos, gidx, sidx, out, M);
        return;
    }

    hist_kernel     <<<NBLK, 256, 0, stream>>>(sidx, histmat, M, NB);
    colscan_kernel  <<<(NB + 255) / 256, 256, 0, stream>>>(histmat, cursors, cnt, NB, NBLK);
    basescan_kernel <<<1, 256, 0, stream>>>(cnt, base, NB);
    partition_kernel<<<NBLK, 256, 0, stream>>>(pos, gidx, sidx, cursors, base, payload, M, NB);
    fused_reduce_kernel<<<NB, 1024, 0, stream>>>(A, B, payload, base, out, K);
}

// Round 6
// 106.991 us; speedup vs baseline: 5.0466x; 1.4613x over previous
//
#include <hip/hip_runtime.h>
#include <hip/hip_bf16.h>

// out[k,s] = sum_{g: seq[g]==k} exp(A[gi,s] + 1 - pos[g]*B[gi,s]),
// N=1000, S=32, M=2M, K=100k.
//
// Round 6: same structure as round 5 (bucket partition + fused sort/reduce,
// zero per-lane atomics). Only change: colscan parallelized 16x (round-5
// profile: 61us at 0.13% occupancy, a 245-long serial load chain per thread).
// 16 sub-threads per bucket, shfl-scan across subs, serial chain -> 16.

#define CHUNK 8192        // genes per partition block
#define NBMAX 1024        // max buckets (K <= 131072)
#define SORTC 3072        // sorted-chunk capacity in fused reduce
#define SUB   16          // sub-threads per bucket in colscan

// ---- 1: per-block histogram -> hist matrix (u16, coalesced) ---------------
__global__ __launch_bounds__(256) void hist_kernel(
    const int* __restrict__ sidx, unsigned short* __restrict__ histmat,
    int M, int NB)
{
    __shared__ int h[NBMAX];
    const int t = threadIdx.x, blk = blockIdx.x;
    const int i0 = blk * CHUNK;
    const int n = min(CHUNK, M - i0);
    for (int j = t; j < NBMAX; j += 256) h[j] = 0;
    __syncthreads();
    for (int j = t; j < n; j += 256) atomicAdd(&h[sidx[i0 + j] >> 7], 1);
    __syncthreads();
    for (int j = t; j < NB; j += 256)
        histmat[(size_t)blk * NB + j] = (unsigned short)h[j];
}

// ---- 2: column-wise exclusive scan over blocks -> cursors + bucket counts -
// 16 threads per bucket; each sums a slice of the block-column, shfl-scan
// combines, each re-walks its slice writing cursors.
__global__ __launch_bounds__(256) void colscan_kernel(
    const unsigned short* __restrict__ histmat, unsigned short* __restrict__ cursors,
    int* __restrict__ cnt, int NB, int NBLK)
{
    const int gid = blockIdx.x * 256 + threadIdx.x;
    const int b = gid / SUB, s = gid & (SUB - 1);
    if (b >= NB) return;
    const int bps = (NBLK + SUB - 1) / SUB;
    const int lo = s * bps, hi = min(lo + bps, NBLK);

    int sum = 0;
    for (int blk = lo; blk < hi; blk++)
        sum += histmat[(size_t)blk * NB + b];

    // inclusive shfl scan over the 16 subs of this bucket
    int incl = sum;
#pragma unroll
    for (int d = 1; d < SUB; d <<= 1) {
        const int x = __shfl_up(incl, d, SUB);
        if (s >= d) incl += x;
    }
    const int excl = incl - sum;
    if (s == SUB - 1) cnt[b] = incl;   // bucket total

    int run = excl;
    for (int blk = lo; blk < hi; blk++) {
        const size_t id = (size_t)blk * NB + b;
        const int v = histmat[id];
        cursors[id] = (unsigned short)run;
        run += v;
    }
}

// ---- 3: exclusive scan of bucket counts -> base[NB+1] ---------------------
__global__ __launch_bounds__(256) void basescan_kernel(
    const int* __restrict__ cnt, int* __restrict__ base, int NB)
{
    __shared__ int ssum[256];
    const int t = threadIdx.x;
    int v[4], s = 0;
#pragma unroll
    for (int j = 0; j < 4; j++) {
        const int idx = t * 4 + j;
        v[j] = (idx < NB) ? cnt[idx] : 0;
        s += v[j];
    }
    ssum[t] = s;
    __syncthreads();
    for (int d = 1; d < 256; d <<= 1) {
        const int x = (t >= d) ? ssum[t - d] : 0;
        __syncthreads();
        ssum[t] += x;
        __syncthreads();
    }
    int run = (t > 0) ? ssum[t - 1] : 0;
#pragma unroll
    for (int j = 0; j < 4; j++) {
        const int idx = t * 4 + j;
        if (idx <= NB) base[idx] = run;   // exclusive prefix; base[NB] = total
        run += v[j];
    }
}

// ---- 4: block-local counting sort -> coalesced payload write --------------
__global__ __launch_bounds__(256) void partition_kernel(
    const float* __restrict__ pos, const int* __restrict__ gidx,
    const int* __restrict__ sidx,
    const unsigned short* __restrict__ cursors, const int* __restrict__ base,
    int2* __restrict__ payload, int M, int NB)
{
    __shared__ int h[NBMAX];      // hist
    __shared__ int pfx[NBMAX];    // exclusive prefix (kept)
    __shared__ int cur[NBMAX];    // cursor for placement, then dest-base
    __shared__ int ssum[256];
    __shared__ int2 stg[CHUNK];   // 64 KB staging
    const int t = threadIdx.x, blk = blockIdx.x;
    const int i0 = blk * CHUNK;
    const int n = min(CHUNK, M - i0);

    for (int j = t; j < NBMAX; j += 256) h[j] = 0;
    __syncthreads();
    for (int j = t; j < n; j += 256) atomicAdd(&h[sidx[i0 + j] >> 7], 1);
    __syncthreads();

    // block scan of h -> pfx, cur
    int v[4], s = 0;
#pragma unroll
    for (int j = 0; j < 4; j++) { v[j] = h[t * 4 + j]; s += v[j]; }
    ssum[t] = s;
    __syncthreads();
    for (int d = 1; d < 256; d <<= 1) {
        const int x = (t >= d) ? ssum[t - d] : 0;
        __syncthreads();
        ssum[t] += x;
        __syncthreads();
    }
    int run = (t > 0) ? ssum[t - 1] : 0;
#pragma unroll
    for (int j = 0; j < 4; j++) {
        pfx[t * 4 + j] = run;
        cur[t * 4 + j] = run;
        run += v[j];
    }
    __syncthreads();

    // placement into LDS staging (sorted by bucket)
    for (int j = t; j < n; j += 256) {
        const int sx = sidx[i0 + j];
        const int b = sx >> 7;
        const int d = atomicAdd(&cur[b], 1);
        int2 pl;
        pl.x = __float_as_int(pos[i0 + j]);
        pl.y = sx | (gidx[i0 + j] << 17);    // sidx: 17 bits, gidx: 14 bits
        stg[d] = pl;
    }
    __syncthreads();

    // precompute per-bucket global destination base into cur[] (coalesced)
    for (int b = t; b < NB; b += 256)
        cur[b] = base[b] + (int)cursors[(size_t)blk * NB + b];
    __syncthreads();

    // coalesced flush: consecutive threads -> consecutive global slots
    for (int tt = t; tt < n; tt += 256) {
        const int2 pl = stg[tt];
        const int b = (pl.y & 0x1FFFF) >> 7;
        payload[cur[b] + (tt - pfx[b])] = pl;
    }
}

// ---- 5: fused per-bucket sort-by-seq + register-accumulate reduce ---------
__global__ __launch_bounds__(1024, 8) void fused_reduce_kernel(
    const float* __restrict__ A, const float* __restrict__ B,
    const int2* __restrict__ payload, const int* __restrict__ base,
    float* __restrict__ out, int K)
{
    __shared__ int2 sorted[SORTC];    // 24 KB
    __shared__ int h[128];            // per-chunk counts per local seq
    __shared__ int pfx[128];          // exclusive prefix
    __shared__ int cur[128];          // scatter cursor
    __shared__ int sc[128];           // scan scratch
    const int t = threadIdx.x, bkt = blockIdx.x;
    const int lane = t & 31, grp = t >> 5;
    const int start = base[bkt], end = base[bkt + 1];

    float acc[4] = {0.0f, 0.0f, 0.0f, 0.0f};

    for (int c = start; c < end; c += SORTC) {
        const int n = min(SORTC, end - c);

        if (t < 128) h[t] = 0;
        __syncthreads();

        // load up to 3 entries/thread (coalesced), LDS int histogram
        int2 r0, r1, r2;
        const bool v0 = t < n, v1 = t + 1024 < n, v2 = t + 2048 < n;
        if (v0) { r0 = payload[c + t];        atomicAdd(&h[r0.y & 127], 1); }
        if (v1) { r1 = payload[c + t + 1024]; atomicAdd(&h[r1.y & 127], 1); }
        if (v2) { r2 = payload[c + t + 2048]; atomicAdd(&h[r2.y & 127], 1); }
        __syncthreads();

        // inclusive scan of h over 128 entries (Hillis-Steele, block-wide)
        if (t < 128) sc[t] = h[t];
        __syncthreads();
        for (int d = 1; d < 128; d <<= 1) {
            int x = 0;
            if (t < 128 && t >= d) x = sc[t - d];
            __syncthreads();
            if (t < 128) sc[t] += x;
            __syncthreads();
        }
        if (t < 128) { pfx[t] = sc[t] - h[t]; cur[t] = sc[t] - h[t]; }
        __syncthreads();

        // scatter into sorted[] by local seq
        if (v0) sorted[atomicAdd(&cur[r0.y & 127], 1)] = r0;
        if (v1) sorted[atomicAdd(&cur[r1.y & 127], 1)] = r1;
        if (v2) sorted[atomicAdd(&cur[r2.y & 127], 1)] = r2;
        __syncthreads();

        // register-accumulate: group grp owns local seqs 4*grp .. 4*grp+3
#pragma unroll
        for (int q = 0; q < 4; q++) {
            const int ls = (grp << 2) | q;
            const int s0 = pfx[ls];
            const int cnt = h[ls];
            for (int i = 0; i < cnt; i++) {
                const int2 pl = sorted[s0 + i];       // ds_read_b64 broadcast
                const float p = __int_as_float(pl.x);
                const int gi = pl.y >> 17;
                const float a = A[(gi << 5) + lane];  // 128B coalesced, L2-hit
                const float b = B[(gi << 5) + lane];
                acc[q] += __expf(fmaf(-p, b, a + 1.0f));
            }
        }
        __syncthreads();   // before next chunk overwrites h/pfx/sorted
    }

    // coalesced stores; every out element covered exactly once -> no memset
    const int seq0 = bkt << 7;
#pragma unroll
    for (int q = 0; q < 4; q++) {
        const int seq = seq0 + (grp << 2) + q;
        if (seq < K) out[(seq << 5) + lane] = acc[q];
    }
}

// ---- fallback (round-1 atomic version) ------------------------------------
__global__ __launch_bounds__(256) void scatter_exp_fallback(
    const float* __restrict__ A, const float* __restrict__ B,
    const float* __restrict__ pos, const int* __restrict__ gidx,
    const int* __restrict__ sidx, float* __restrict__ out, int M)
{
    const int lane = threadIdx.x & 31;
    int group = (int)((blockIdx.x * blockDim.x + threadIdx.x) >> 5);
    const int stride = (int)((gridDim.x * blockDim.x) >> 5);
    for (int g = group; g < M; g += stride) {
        const int gi = gidx[g];
        const int si = sidx[g];
        const float p = pos[g];
        const float a = A[(gi << 5) + lane];
        const float b = B[(gi << 5) + lane];
        atomicAdd(&out[(si << 5) + lane], __expf(fmaf(-p, b, a + 1.0f)));
    }
}

extern "C" void kernel_launch(void* const* d_in, const int* in_sizes, int n_in,
                              void* d_out, int out_size, void* d_ws, size_t ws_size,
                              hipStream_t stream)
{
    const float* A    = (const float*)d_in[0];   // [N,32]
    const float* B    = (const float*)d_in[1];   // [N,32]
    const float* pos  = (const float*)d_in[2];   // [M]
    const int*   gidx = (const int*)d_in[3];     // [M]
    const int*   sidx = (const int*)d_in[4];     // [M]
    float*       out  = (float*)d_out;           // [K,32]

    const int M = in_sizes[2];
    const int N = in_sizes[0] / 32;
    const int K = out_size / 32;
    const int NB = (K + 127) >> 7;               // 782 for K=100k
    const int NBLK = (M + CHUNK - 1) / CHUNK;    // 245 for M=2M

    // ws layout: histmat u16[NBLK*NB] | cursors u16[NBLK*NB] | cnt i32[1024]
    //            | base i32[1025] | payload int2[M]
    char* ws = (char*)d_ws;
    const size_t matbytes = (size_t)NBLK * NB * sizeof(unsigned short);
    unsigned short* histmat = (unsigned short*)ws;
    unsigned short* cursors = (unsigned short*)(ws + matbytes);
    size_t off = 2 * matbytes;
    off = (off + 3) & ~(size_t)3;
    int* cnt  = (int*)(ws + off);  off += (size_t)NBMAX * sizeof(int);
    int* base = (int*)(ws + off);  off += (size_t)(NBMAX + 1) * sizeof(int);
    off = (off + 15) & ~(size_t)15;
    int2* payload = (int2*)(ws + off);
    const size_t need = off + (size_t)M * sizeof(int2);

    // pack limits: sidx 17 bits (K<=131072), gidx 14 bits (N<=16384)
    const bool packable = (NB <= NBMAX) && (K <= 131072) && (N <= 16384);
    if (!packable || ws_size < need) {
        hipMemsetAsync(d_out, 0, (size_t)out_size * sizeof(float), stream);
        scatter_exp_fallback<<<8192, 256, 0, stream>>>(A, B, pos, gidx, sidx, out, M);
        return;
    }

    hist_kernel     <<<NBLK, 256, 0, stream>>>(sidx, histmat, M, NB);
    colscan_kernel  <<<(NB * SUB + 255) / 256, 256, 0, stream>>>(histmat, cursors, cnt, NB, NBLK);
    basescan_kernel <<<1, 256, 0, stream>>>(cnt, base, NB);
    partition_kernel<<<NBLK, 256, 0, stream>>>(pos, gidx, sidx, cursors, base, payload, M, NB);
    fused_reduce_kernel<<<NB, 1024, 0, stream>>>(A, B, payload, base, out, K);
}

// Round 7
// 76.022 us; speedup vs baseline: 7.1023x; 1.4074x over previous
//
#include <hip/hip_runtime.h>
#include <hip/hip_bf16.h>

// out[k,s] = sum_{g: seq[g]==k} exp(A[gi,s] + 1 - pos[g]*B[gi,s]),
// N=1000, S=32, M=2M, K=100k.
//
// Round 7: same 5-stage structure as r5/r6 (bucket partition, fused
// sort+register reduce, zero per-lane atomics). Changes:
//  - payload packed to u32: local_seq(7) | gidx(10) | pos_q15(15);
//    pos quantization err 3e-5 << 2% threshold. Halves payload BW + LDS.
//  - AB2 precompute: A2=(A+1)*log2e, B2=B*log2e/32768 interleaved [N][2][32];
//    inner loop = cvt + fmaf + v_exp_f32 (base-2, inline asm).
//  - dual-accumulator unroll-2 in reduce for 2 independent load/exp chains.
//  - hist/partition at 1024 threads (were 256: 1 wave/SIMD on single-resident
//    CUs = no latency hiding); wave-shfl scans replace barrier scans.

#define CHUNK 8192        // genes per partition block
#define NBMAX 1024        // max buckets (K <= 131072)
#define SORTC 4096        // sorted-chunk capacity in fused reduce (u32)
#define SUB   16          // sub-threads per bucket in colscan

__device__ inline float fast_exp2(float x) {
    float r;
    asm("v_exp_f32 %0, %1" : "=v"(r) : "v"(x));
    return r;
}

// ---- 0: precompute AB2[gi*64 + lane] = (A+1)*log2e ; [.. +32] = B*log2e/2^15
__global__ __launch_bounds__(256) void prep_kernel(
    const float* __restrict__ A, const float* __restrict__ B,
    float* __restrict__ AB2, int NS)
{
    const int i = blockIdx.x * 256 + threadIdx.x;
    if (i >= NS) return;
    const int gi = i >> 5, lane = i & 31;
    AB2[(gi << 6) + lane]      = (A[i] + 1.0f) * 1.44269504f;
    AB2[(gi << 6) + 32 + lane] = B[i] * (1.44269504f / 32768.0f);
}

// ---- 1: per-block histogram -> hist matrix (u16, coalesced) ---------------
__global__ __launch_bounds__(1024) void hist_kernel(
    const int* __restrict__ sidx, unsigned short* __restrict__ histmat,
    int M, int NB)
{
    __shared__ int h[NBMAX];
    const int t = threadIdx.x, blk = blockIdx.x;
    const int i0 = blk * CHUNK;
    const int n = min(CHUNK, M - i0);
    h[t] = 0;
    __syncthreads();
    for (int j = t; j < n; j += 1024) atomicAdd(&h[sidx[i0 + j] >> 7], 1);
    __syncthreads();
    for (int j = t; j < NB; j += 1024)
        histmat[(size_t)blk * NB + j] = (unsigned short)h[j];
}

// ---- 2: column-wise exclusive scan over blocks -> cursors + bucket counts -
__global__ __launch_bounds__(256) void colscan_kernel(
    const unsigned short* __restrict__ histmat, unsigned short* __restrict__ cursors,
    int* __restrict__ cnt, int NB, int NBLK)
{
    const int gid = blockIdx.x * 256 + threadIdx.x;
    const int b = gid / SUB, s = gid & (SUB - 1);
    if (b >= NB) return;
    const int bps = (NBLK + SUB - 1) / SUB;
    const int lo = s * bps, hi = min(lo + bps, NBLK);

    int sum = 0;
    for (int blk = lo; blk < hi; blk++)
        sum += histmat[(size_t)blk * NB + b];

    int incl = sum;
#pragma unroll
    for (int d = 1; d < SUB; d <<= 1) {
        const int x = __shfl_up(incl, d, SUB);
        if (s >= d) incl += x;
    }
    const int excl = incl - sum;
    if (s == SUB - 1) cnt[b] = incl;

    int run = excl;
    for (int blk = lo; blk < hi; blk++) {
        const size_t id = (size_t)blk * NB + b;
        const int v = histmat[id];
        cursors[id] = (unsigned short)run;
        run += v;
    }
}

// ---- 3: exclusive scan of bucket counts -> base[NB+1] ---------------------
__global__ __launch_bounds__(256) void basescan_kernel(
    const int* __restrict__ cnt, int* __restrict__ base, int NB)
{
    __shared__ int ssum[256];
    const int t = threadIdx.x;
    int v[4], s = 0;
#pragma unroll
    for (int j = 0; j < 4; j++) {
        const int idx = t * 4 + j;
        v[j] = (idx < NB) ? cnt[idx] : 0;
        s += v[j];
    }
    ssum[t] = s;
    __syncthreads();
    for (int d = 1; d < 256; d <<= 1) {
        const int x = (t >= d) ? ssum[t - d] : 0;
        __syncthreads();
        ssum[t] += x;
        __syncthreads();
    }
    int run = (t > 0) ? ssum[t - 1] : 0;
#pragma unroll
    for (int j = 0; j < 4; j++) {
        const int idx = t * 4 + j;
        if (idx <= NB) base[idx] = run;
        run += v[j];
    }
}

// ---- 4: block-local counting sort -> coalesced u32 payload write ----------
__global__ __launch_bounds__(1024) void partition_kernel(
    const float* __restrict__ pos, const int* __restrict__ gidx,
    const int* __restrict__ sidx,
    const unsigned short* __restrict__ cursors, const int* __restrict__ base,
    unsigned* __restrict__ payload, int M, int NB)
{
    __shared__ int h[NBMAX];
    __shared__ int pfx[NBMAX];
    __shared__ int cur[NBMAX];
    __shared__ int wsum[16];
    __shared__ unsigned stg_p[CHUNK];        // 32 KB packed payload
    __shared__ unsigned short stg_b[CHUNK];  // 16 KB bucket of each slot
    const int t = threadIdx.x, blk = blockIdx.x;
    const int i0 = blk * CHUNK;
    const int n = min(CHUNK, M - i0);

    h[t] = 0;
    __syncthreads();
    for (int j = t; j < n; j += 1024) atomicAdd(&h[sidx[i0 + j] >> 7], 1);
    __syncthreads();

    // block-wide exclusive scan over 1024 entries: wave shfl-scan + wave sums
    {
        const int v = h[t];
        int incl = v;
#pragma unroll
        for (int d = 1; d < 64; d <<= 1) {
            const int x = __shfl_up(incl, d);
            if ((t & 63) >= d) incl += x;
        }
        if ((t & 63) == 63) wsum[t >> 6] = incl;
        __syncthreads();
        if (t < 16) {
            const int wv = wsum[t];
            int winc = wv;
#pragma unroll
            for (int d = 1; d < 16; d <<= 1) {
                const int x = __shfl_up(winc, d, 16);
                if (t >= d) winc += x;
            }
            wsum[t] = winc - wv;   // exclusive wave base
        }
        __syncthreads();
        const int ex = wsum[t >> 6] + incl - v;
        pfx[t] = ex;
        cur[t] = ex;
    }
    __syncthreads();

    // placement into LDS staging (sorted by bucket), pack to u32
    for (int j = t; j < n; j += 1024) {
        const int sx = sidx[i0 + j];
        const int b = sx >> 7;
        const float p = pos[i0 + j];
        int q = (int)fmaf(p, 32768.0f, 0.5f);
        q = min(q, 32767);
        const unsigned pl = (unsigned)(sx & 127)
                          | ((unsigned)gidx[i0 + j] << 7)
                          | ((unsigned)q << 17);
        const int d = atomicAdd(&cur[b], 1);
        stg_p[d] = pl;
        stg_b[d] = (unsigned short)b;
    }
    __syncthreads();

    // per-bucket global destination base into cur[] (coalesced reads)
    for (int b = t; b < NB; b += 1024)
        cur[b] = base[b] + (int)cursors[(size_t)blk * NB + b];
    __syncthreads();

    // coalesced flush
    for (int tt = t; tt < n; tt += 1024) {
        const int b = stg_b[tt];
        payload[cur[b] + (tt - pfx[b])] = stg_p[tt];
    }
}

// ---- 5: fused per-bucket sort-by-seq + register-accumulate reduce ---------
__global__ __launch_bounds__(1024, 8) void fused_reduce_kernel(
    const float* __restrict__ AB2, const unsigned* __restrict__ payload,
    const int* __restrict__ base, float* __restrict__ out, int K)
{
    __shared__ unsigned sorted[SORTC];   // 16 KB
    __shared__ int h[128];
    __shared__ int pfx[128];
    __shared__ int cur[128];
    const int t = threadIdx.x, bkt = blockIdx.x;
    const int lane = t & 31, grp = t >> 5;
    const int start = base[bkt], end = base[bkt + 1];

    float acc[4] = {0.0f, 0.0f, 0.0f, 0.0f};

    for (int c = start; c < end; c += SORTC) {
        const int n = min(SORTC, end - c);

        if (t < 128) h[t] = 0;
        __syncthreads();

        unsigned r0, r1, r2, r3;
        const bool v0 = t < n, v1 = t + 1024 < n, v2 = t + 2048 < n, v3 = t + 3072 < n;
        if (v0) { r0 = payload[c + t];        atomicAdd(&h[r0 & 127], 1); }
        if (v1) { r1 = payload[c + t + 1024]; atomicAdd(&h[r1 & 127], 1); }
        if (v2) { r2 = payload[c + t + 2048]; atomicAdd(&h[r2 & 127], 1); }
        if (v3) { r3 = payload[c + t + 3072]; atomicAdd(&h[r3 & 127], 1); }
        __syncthreads();

        // 128-entry exclusive scan by wave 0 (shfl, no barriers inside)
        if (t < 64) {
            const int e0 = h[2 * t], e1 = h[2 * t + 1];
            const int ps = e0 + e1;
            int incl = ps;
#pragma unroll
            for (int d = 1; d < 64; d <<= 1) {
                const int x = __shfl_up(incl, d);
                if (t >= d) incl += x;
            }
            const int ex = incl - ps;
            pfx[2 * t] = ex;          cur[2 * t] = ex;
            pfx[2 * t + 1] = ex + e0; cur[2 * t + 1] = ex + e0;
        }
        __syncthreads();

        if (v0) sorted[atomicAdd(&cur[r0 & 127], 1)] = r0;
        if (v1) sorted[atomicAdd(&cur[r1 & 127], 1)] = r1;
        if (v2) sorted[atomicAdd(&cur[r2 & 127], 1)] = r2;
        if (v3) sorted[atomicAdd(&cur[r3 & 127], 1)] = r3;
        __syncthreads();

        // register-accumulate: group owns local seqs 4*grp..4*grp+3;
        // unroll-2 with dual accumulators for independent load/exp chains
#pragma unroll
        for (int q = 0; q < 4; q++) {
            const int ls = (grp << 2) | q;
            int i = pfx[ls];
            const int e = i + h[ls];
            float a0 = 0.0f, a1 = 0.0f;
            for (; i + 1 < e; i += 2) {
                const unsigned w0 = sorted[i], w1 = sorted[i + 1];
                const float q0 = (float)(w0 >> 17);
                const float q1 = (float)(w1 >> 17);
                const int b0 = (int)(((w0 >> 7) & 1023) << 6) + lane;
                const int b1 = (int)(((w1 >> 7) & 1023) << 6) + lane;
                const float x0 = fmaf(-q0, AB2[b0 + 32], AB2[b0]);
                const float x1 = fmaf(-q1, AB2[b1 + 32], AB2[b1]);
                a0 += fast_exp2(x0);
                a1 += fast_exp2(x1);
            }
            if (i < e) {
                const unsigned w0 = sorted[i];
                const float q0 = (float)(w0 >> 17);
                const int b0 = (int)(((w0 >> 7) & 1023) << 6) + lane;
                a0 += fast_exp2(fmaf(-q0, AB2[b0 + 32], AB2[b0]));
            }
            acc[q] += a0 + a1;
        }
        __syncthreads();
    }

    const int seq0 = bkt << 7;
#pragma unroll
    for (int q = 0; q < 4; q++) {
        const int seq = seq0 + (grp << 2) + q;
        if (seq < K) out[(seq << 5) + lane] = acc[q];
    }
}

// ---- fallback (round-1 atomic version) ------------------------------------
__global__ __launch_bounds__(256) void scatter_exp_fallback(
    const float* __restrict__ A, const float* __restrict__ B,
    const float* __restrict__ pos, const int* __restrict__ gidx,
    const int* __restrict__ sidx, float* __restrict__ out, int M)
{
    const int lane = threadIdx.x & 31;
    int group = (int)((blockIdx.x * blockDim.x + threadIdx.x) >> 5);
    const int stride = (int)((gridDim.x * blockDim.x) >> 5);
    for (int g = group; g < M; g += stride) {
        const int gi = gidx[g];
        const int si = sidx[g];
        const float p = pos[g];
        const float a = A[(gi << 5) + lane];
        const float b = B[(gi << 5) + lane];
        atomicAdd(&out[(si << 5) + lane], __expf(fmaf(-p, b, a + 1.0f)));
    }
}

extern "C" void kernel_launch(void* const* d_in, const int* in_sizes, int n_in,
                              void* d_out, int out_size, void* d_ws, size_t ws_size,
                              hipStream_t stream)
{
    const float* A    = (const float*)d_in[0];   // [N,32]
    const float* B    = (const float*)d_in[1];   // [N,32]
    const float* pos  = (const float*)d_in[2];   // [M]
    const int*   gidx = (const int*)d_in[3];     // [M]
    const int*   sidx = (const int*)d_in[4];     // [M]
    float*       out  = (float*)d_out;           // [K,32]

    const int M  = in_sizes[2];
    const int NS = in_sizes[0];                  // N*32
    const int N  = NS / 32;
    const int K  = out_size / 32;
    const int NB = (K + 127) >> 7;               // 782 for K=100k
    const int NBLK = (M + CHUNK - 1) / CHUNK;    // 245 for M=2M

    // ws layout: histmat u16[NBLK*NB] | cursors u16[NBLK*NB] | cnt i32[1024]
    //            | base i32[1025] | AB2 f32[N*64] | payload u32[M]
    char* ws = (char*)d_ws;
    const size_t matbytes = (size_t)NBLK * NB * sizeof(unsigned short);
    unsigned short* histmat = (unsigned short*)ws;
    unsigned short* cursors = (unsigned short*)(ws + matbytes);
    size_t off = 2 * matbytes;
    off = (off + 3) & ~(size_t)3;
    int* cnt  = (int*)(ws + off);  off += (size_t)NBMAX * sizeof(int);
    int* base = (int*)(ws + off);  off += (size_t)(NBMAX + 1) * sizeof(int);
    off = (off + 255) & ~(size_t)255;
    float* AB2 = (float*)(ws + off); off += (size_t)N * 64 * sizeof(float);
    off = (off + 255) & ~(size_t)255;
    unsigned* payload = (unsigned*)(ws + off);
    const size_t need = off + (size_t)M * sizeof(unsigned);

    // pack limits: local seq 7b (by construction), gidx 10b, pos_q 15b
    const bool packable = (NB <= NBMAX) && (K <= NBMAX * 128) && (N <= 1024);
    if (!packable || ws_size < need) {
        hipMemsetAsync(d_out, 0, (size_t)out_size * sizeof(float), stream);
        scatter_exp_fallback<<<8192, 256, 0, stream>>>(A, B, pos, gidx, sidx, out, M);
        return;
    }

    prep_kernel     <<<(NS + 255) / 256, 256, 0, stream>>>(A, B, AB2, NS);
    hist_kernel     <<<NBLK, 1024, 0, stream>>>(sidx, histmat, M, NB);
    colscan_kernel  <<<(NB * SUB + 255) / 256, 256, 0, stream>>>(histmat, cursors, cnt, NB, NBLK);
    basescan_kernel <<<1, 256, 0, stream>>>(cnt, base, NB);
    partition_kernel<<<NBLK, 1024, 0, stream>>>(pos, gidx, sidx, cursors, base, payload, M, NB);
    fused_reduce_kernel<<<NB, 1024, 0, stream>>>(AB2, payload, base, out, K);
}

// Round 8
// 67.599 us; speedup vs baseline: 7.9874x; 1.1246x over previous
//
#include <hip/hip_runtime.h>
#include <hip/hip_bf16.h>

// out[k,s] = sum_{g: seq[g]==k} exp(A[gi,s] + 1 - pos[g]*B[gi,s]),
// N=1000, S=32, M=2M, K=100k.
//
// Round 8 (structure: bucket partition + fused sort/register-reduce, zero
// per-lane atomics). Changes vs r7:
//  - AB2 packed to ONE u32 per (genome,lane): f16(a2) | bf16bits(b2)<<16.
//    Halves the reduce's L2 gather traffic (512->256 MB) and removes a load.
//  - hist/colscan/basescan kernels DELETED: partition atomically claims
//    per-bucket ranges in fixed 4096-entry regions (gcur[b]); mean bucket
//    fill 2560, 30-sigma headroom, plus write guard.
//  - reduce LDS down to ~17.5 KB -> 2 blocks/CU (32 waves) for latency hiding.

#define CHUNK 8192        // genes per partition block
#define NBMAX 1024        // max buckets (K <= 131072)
#define CAPLG 12          // per-bucket region = 4096 entries
#define CAP   (1 << CAPLG)
#define SORTC 4096        // sorted-chunk capacity in fused reduce (u32)

__device__ inline float fast_exp2(float x) {
    float r;
    asm("v_exp_f32 %0, %1" : "=v"(r) : "v"(x));
    return r;
}

// ---- 0: pack AB2p[gi*32+lane] = f16((A+1)*log2e) | bf16(B*log2e/2^15)<<16
__global__ __launch_bounds__(256) void prep_kernel(
    const float* __restrict__ A, const float* __restrict__ B,
    unsigned* __restrict__ AB2p, int NS)
{
    const int i = blockIdx.x * 256 + threadIdx.x;
    if (i >= NS) return;
    const int gi = i >> 5, lane = i & 31;
    const float a2 = (A[i] + 1.0f) * 1.44269504f;
    const float b2 = B[i] * (1.44269504f / 32768.0f);
    const _Float16 ha = (_Float16)a2;                       // RNE cvt
    const unsigned short ua = __builtin_bit_cast(unsigned short, ha);
    unsigned bb = __float_as_uint(b2);
    bb = (bb + 0x7FFFu + ((bb >> 16) & 1u)) & 0xFFFF0000u;  // RNE to bf16
    AB2p[(gi << 5) + lane] = (unsigned)ua | bb;
}

// ---- 1: block-local counting sort by bucket + atomic range claim ----------
__global__ __launch_bounds__(1024) void partition_kernel(
    const float* __restrict__ pos, const int* __restrict__ gidx,
    const int* __restrict__ sidx, int* __restrict__ gcur,
    unsigned* __restrict__ payload, int M, int NB)
{
    __shared__ int h[NBMAX];
    __shared__ int pfx[NBMAX];
    __shared__ int cur[NBMAX];
    __shared__ int wsum[16];
    __shared__ unsigned stg_p[CHUNK];        // 32 KB packed payload
    __shared__ unsigned short stg_b[CHUNK];  // 16 KB bucket of each slot
    const int t = threadIdx.x, blk = blockIdx.x;
    const int i0 = blk * CHUNK;
    const int n = min(CHUNK, M - i0);

    h[t] = 0;
    __syncthreads();
    for (int j = t; j < n; j += 1024) atomicAdd(&h[sidx[i0 + j] >> 7], 1);
    __syncthreads();

    // block-wide exclusive scan over 1024 entries (wave shfl + wave sums)
    int incl;
    {
        const int v = h[t];
        incl = v;
#pragma unroll
        for (int d = 1; d < 64; d <<= 1) {
            const int x = __shfl_up(incl, d);
            if ((t & 63) >= d) incl += x;
        }
        if ((t & 63) == 63) wsum[t >> 6] = incl;
        __syncthreads();
        if (t < 16) {
            const int wv = wsum[t];
            int winc = wv;
#pragma unroll
            for (int d = 1; d < 16; d <<= 1) {
                const int x = __shfl_up(winc, d, 16);
                if (t >= d) winc += x;
            }
            wsum[t] = winc - wv;
        }
        __syncthreads();
        const int ex = wsum[t >> 6] + incl - h[t];
        pfx[t] = ex;
        cur[t] = ex;
    }
    __syncthreads();

    // placement into LDS staging (sorted by bucket), pack payload u32:
    // local_seq(7) | gidx(10) | pos_q15(15)
    for (int j = t; j < n; j += 1024) {
        const int sx = sidx[i0 + j];
        const int b = sx >> 7;
        const float p = pos[i0 + j];
        int q = (int)fmaf(p, 32768.0f, 0.5f);
        q = min(q, 32767);
        const unsigned pl = (unsigned)(sx & 127)
                          | ((unsigned)gidx[i0 + j] << 7)
                          | ((unsigned)q << 17);
        const int d = atomicAdd(&cur[b], 1);
        stg_p[d] = pl;
        stg_b[d] = (unsigned short)b;
    }
    __syncthreads();

    // claim this block's range in each bucket's fixed region
    if (t < NB) {
        const int hc = h[t];
        int dst = t << CAPLG;
        if (hc > 0) dst += atomicAdd(&gcur[t], hc);
        cur[t] = dst;
    }
    __syncthreads();

    // coalesced flush; guard against (statistically impossible) overflow
    for (int tt = t; tt < n; tt += 1024) {
        const int b = stg_b[tt];
        const int r = cur[b] + (tt - pfx[b]);
        if ((r >> CAPLG) == b) payload[r] = stg_p[tt];
    }
}

// ---- 2: fused per-bucket sort-by-seq + register-accumulate reduce ---------
__global__ __launch_bounds__(1024, 8) void fused_reduce_kernel(
    const unsigned* __restrict__ AB2p, const unsigned* __restrict__ payload,
    const int* __restrict__ gcur, float* __restrict__ out, int K)
{
    __shared__ unsigned sorted[SORTC];   // 16 KB
    __shared__ int h[128];
    __shared__ int pfx[128];
    __shared__ int cur[128];
    const int t = threadIdx.x, bkt = blockIdx.x;
    const int lane = t & 31, grp = t >> 5;
    const int start = bkt << CAPLG;
    const int n_total = min(gcur[bkt], CAP);

    float acc[4] = {0.0f, 0.0f, 0.0f, 0.0f};

    for (int c = start; c < start + n_total; c += SORTC) {
        const int n = min(SORTC, start + n_total - c);

        if (t < 128) h[t] = 0;
        __syncthreads();

        unsigned r0, r1, r2, r3;
        const bool v0 = t < n, v1 = t + 1024 < n, v2 = t + 2048 < n, v3 = t + 3072 < n;
        if (v0) { r0 = payload[c + t];        atomicAdd(&h[r0 & 127], 1); }
        if (v1) { r1 = payload[c + t + 1024]; atomicAdd(&h[r1 & 127], 1); }
        if (v2) { r2 = payload[c + t + 2048]; atomicAdd(&h[r2 & 127], 1); }
        if (v3) { r3 = payload[c + t + 3072]; atomicAdd(&h[r3 & 127], 1); }
        __syncthreads();

        // 128-entry exclusive scan by wave 0 (shfl, no barriers inside)
        if (t < 64) {
            const int e0 = h[2 * t], e1 = h[2 * t + 1];
            const int ps = e0 + e1;
            int incl = ps;
#pragma unroll
            for (int d = 1; d < 64; d <<= 1) {
                const int x = __shfl_up(incl, d);
                if (t >= d) incl += x;
            }
            const int ex = incl - ps;
            pfx[2 * t] = ex;          cur[2 * t] = ex;
            pfx[2 * t + 1] = ex + e0; cur[2 * t + 1] = ex + e0;
        }
        __syncthreads();

        if (v0) sorted[atomicAdd(&cur[r0 & 127], 1)] = r0;
        if (v1) sorted[atomicAdd(&cur[r1 & 127], 1)] = r1;
        if (v2) sorted[atomicAdd(&cur[r2 & 127], 1)] = r2;
        if (v3) sorted[atomicAdd(&cur[r3 & 127], 1)] = r3;
        __syncthreads();

        // register-accumulate: group owns local seqs 4*grp..4*grp+3;
        // unroll-2 dual accumulators = 2 independent load/exp chains
#pragma unroll
        for (int q = 0; q < 4; q++) {
            const int ls = (grp << 2) | q;
            int i = pfx[ls];
            const int e = i + h[ls];
            float a0 = 0.0f, a1 = 0.0f;
            for (; i + 1 < e; i += 2) {
                const unsigned w0 = sorted[i], w1 = sorted[i + 1];   // ds_read_b64
                const float q0 = (float)(w0 >> 17);
                const float q1 = (float)(w1 >> 17);
                const unsigned ab0 = AB2p[(int)(((w0 >> 7) & 1023) << 5) + lane];
                const unsigned ab1 = AB2p[(int)(((w1 >> 7) & 1023) << 5) + lane];
                float a2_0, a2_1;
                asm("v_cvt_f32_f16 %0, %1" : "=v"(a2_0) : "v"(ab0));
                asm("v_cvt_f32_f16 %0, %1" : "=v"(a2_1) : "v"(ab1));
                const float b2_0 = __int_as_float(ab0 & 0xFFFF0000u);
                const float b2_1 = __int_as_float(ab1 & 0xFFFF0000u);
                a0 += fast_exp2(fmaf(-q0, b2_0, a2_0));
                a1 += fast_exp2(fmaf(-q1, b2_1, a2_1));
            }
            if (i < e) {
                const unsigned w0 = sorted[i];
                const float q0 = (float)(w0 >> 17);
                const unsigned ab0 = AB2p[(int)(((w0 >> 7) & 1023) << 5) + lane];
                float a2_0;
                asm("v_cvt_f32_f16 %0, %1" : "=v"(a2_0) : "v"(ab0));
                a0 += fast_exp2(fmaf(-q0, __int_as_float(ab0 & 0xFFFF0000u), a2_0));
            }
            acc[q] += a0 + a1;
        }
        __syncthreads();
    }

    const int seq0 = bkt << 7;
#pragma unroll
    for (int q = 0; q < 4; q++) {
        const int seq = seq0 + (grp << 2) + q;
        if (seq < K) out[(seq << 5) + lane] = acc[q];
    }
}

// ---- fallback (round-1 atomic version) ------------------------------------
__global__ __launch_bounds__(256) void scatter_exp_fallback(
    const float* __restrict__ A, const float* __restrict__ B,
    const float* __restrict__ pos, const int* __restrict__ gidx,
    const int* __restrict__ sidx, float* __restrict__ out, int M)
{
    const int lane = threadIdx.x & 31;
    int group = (int)((blockIdx.x * blockDim.x + threadIdx.x) >> 5);
    const int stride = (int)((gridDim.x * blockDim.x) >> 5);
    for (int g = group; g < M; g += stride) {
        const int gi = gidx[g];
        const int si = sidx[g];
        const float p = pos[g];
        const float a = A[(gi << 5) + lane];
        const float b = B[(gi << 5) + lane];
        atomicAdd(&out[(si << 5) + lane], __expf(fmaf(-p, b, a + 1.0f)));
    }
}

extern "C" void kernel_launch(void* const* d_in, const int* in_sizes, int n_in,
                              void* d_out, int out_size, void* d_ws, size_t ws_size,
                              hipStream_t stream)
{
    const float* A    = (const float*)d_in[0];   // [N,32]
    const float* B    = (const float*)d_in[1];   // [N,32]
    const float* pos  = (const float*)d_in[2];   // [M]
    const int*   gidx = (const int*)d_in[3];     // [M]
    const int*   sidx = (const int*)d_in[4];     // [M]
    float*       out  = (float*)d_out;           // [K,32]

    const int M  = in_sizes[2];
    const int NS = in_sizes[0];                  // N*32
    const int N  = NS / 32;
    const int K  = out_size / 32;
    const int NB = (K + 127) >> 7;               // 782 for K=100k
    const int NBLK = (M + CHUNK - 1) / CHUNK;    // 245 for M=2M

    // ws layout: gcur i32[NBMAX] | AB2p u32[N*32] | payload u32[NB<<CAPLG]
    char* ws = (char*)d_ws;
    size_t off = 0;
    int* gcur = (int*)(ws + off);       off += (size_t)NBMAX * sizeof(int);
    off = (off + 255) & ~(size_t)255;
    unsigned* AB2p = (unsigned*)(ws + off); off += (size_t)N * 32 * sizeof(unsigned);
    off = (off + 255) & ~(size_t)255;
    unsigned* payload = (unsigned*)(ws + off);
    const size_t need = off + ((size_t)NB << CAPLG) * sizeof(unsigned);

    // pack limits: local seq 7b, gidx 10b (N<=1024), pos_q 15b; mean bucket
    // fill M/NB must be well under CAP (guarded writes handle the tail)
    const bool packable = (NB <= NBMAX) && (K <= NBMAX * 128) && (N <= 1024)
                       && (M / (NB > 0 ? NB : 1) <= CAP / 4 * 3);
    if (!packable || ws_size < need) {
        hipMemsetAsync(d_out, 0, (size_t)out_size * sizeof(float), stream);
        scatter_exp_fallback<<<8192, 256, 0, stream>>>(A, B, pos, gidx, sidx, out, M);
        return;
    }

    hipMemsetAsync(gcur, 0, (size_t)NBMAX * sizeof(int), stream);
    prep_kernel     <<<(NS + 255) / 256, 256, 0, stream>>>(A, B, AB2p, NS);
    partition_kernel<<<NBLK, 1024, 0, stream>>>(pos, gidx, sidx, gcur, payload, M, NB);
    fused_reduce_kernel<<<NB, 1024, 0, stream>>>(AB2p, payload, gcur, out, K);
}